// Round 5
// baseline (150.980 us; speedup 1.0000x reference)
//
#include <hip/hip_runtime.h>

// CRF NLL: forward algorithm (linear-space, rescaled) + gold score.
// B=128 batches, S=512 steps, T=36 states (START=34, END=35).
// One wave per batch; lane j owns state j.  q_j = exp(alpha_j - C).
// Step: q' = (q . M) * exp(f_t),  M = exp(trans).
//
// History: R2/R3 ran 402 cyc/step at ~47% issue efficiency (single wave,
// nothing to hide latency). R3 killed spills (VGPR 40->132, waves_per_eu(1,1))
// with almost no gain -> the stall is NOT spill. R4 theory: scheduler emits
// readlane;fma pairs through one SGPR -> VALU-write-SGPR/VALU-read-SGPR
// hazard wait states x36 per step. Fix: (a) 36 readlanes into 36 DISTINCT
// named scalars, sched_barrier(0), then 36 fmas (producer-consumer distance
// >= 36 instrs, no hazard); (b) exp(f) hoisted out of the serial chain --
// computed once per 8-step phase from prefetched feats.

namespace {
constexpr int kB = 128;
constexpr int kS = 512;
constexpr int kT = 36;
constexpr int kStart = 34;
constexpr int kEnd = 35;

__device__ __forceinline__ float readlane_f(float v, int lane) {
    return __builtin_bit_cast(float, __builtin_amdgcn_readlane(__builtin_bit_cast(int, v), lane));
}

__device__ __forceinline__ float wave_sum(float v) {
#pragma unroll
    for (int off = 32; off; off >>= 1) v += __shfl_xor(v, off, 64);
    return v;
}

__device__ __forceinline__ int wave_sum_i(int v) {
#pragma unroll
    for (int off = 32; off; off >>= 1) v += __shfl_xor(v, off, 64);
    return v;
}

// n = term index, a = accumulator index (rotates 0..3 to break fma chains)
#define FOR36(X) \
    X(0, 0) X(1, 1) X(2, 2) X(3, 3) X(4, 0) X(5, 1) X(6, 2) X(7, 3) \
    X(8, 0) X(9, 1) X(10, 2) X(11, 3) X(12, 0) X(13, 1) X(14, 2) X(15, 3) \
    X(16, 0) X(17, 1) X(18, 2) X(19, 3) X(20, 0) X(21, 1) X(22, 2) X(23, 3) \
    X(24, 0) X(25, 1) X(26, 2) X(27, 3) X(28, 0) X(29, 1) X(30, 2) X(31, 3) \
    X(32, 0) X(33, 1) X(34, 2) X(35, 3)

#define MDECL(n, a) float m##n;
#define MINIT(n, a) m##n = __expf(trans[(n)*kT + jc]);
#define BDECL(n, a) float b##n;
#define BRD(n, a)  b##n = readlane_f(q, n);
#define FMA(n, a)  v##a = fmaf(b##n, m##n, v##a);

__global__ __attribute__((amdgpu_flat_work_group_size(64, 64),
                          amdgpu_waves_per_eu(1, 1)))
void crf_nll_kernel(
    const float* __restrict__ feats,   // (B,S,T)
    const float* __restrict__ trans,   // (T,T)  [i,j] = prev i -> cur j
    const int* __restrict__ mask,      // (B,S)  contiguous prefix
    const int* __restrict__ tags,      // (B,S)
    float* __restrict__ out) {         // scalar
    const int b = blockIdx.x;
    const int j = threadIdx.x;                  // lane = state index
    const int jc = (j < kT) ? j : (kT - 1);     // lanes >= 36 mirror state 35
    const float* fbase = feats + (size_t)b * kS * kT;
    const float* fl = fbase + jc;               // per-lane feats column
    const int* mb = mask + b * kS;
    const int* tb = tags + b * kS;

    // ---- sequence length (contiguous-prefix mask) ----
    int len = 0;
    for (int k = j; k < kS; k += 64) len += mb[k];
    len = wave_sum_i(len);  // len in [256, 512]
    const int tmax = len;

    // ---- M = exp(trans) column jc, in 36 named registers ----
    FOR36(MDECL)
    FOR36(MINIT)
    const float ME = (j < kT) ? __expf(trans[j * kT + kEnd]) : 0.f;

    // ---- init: alpha0 = feats[b,0,:] + trans[START,:] ----
    const float a0 = fl[0] + trans[kStart * kT + jc];
    float C = readlane_f(a0, 0);
    float q = __expf(a0 - C);

    // one step: q' = (q . M) * ef  (ef = exp(f_t), precomputed off-chain)
    auto dostep = [&](float ef, int t) {
        FOR36(BDECL)
        FOR36(BRD)                         // 36 readlanes -> 36 distinct SGPRs
        __builtin_amdgcn_sched_barrier(0); // keep fmas from pairing w/ readlanes
        float v0 = 0.f, v1 = 0.f, v2 = 0.f, v3 = 0.f;
        FOR36(FMA)
        const float nq = ((v0 + v1) + (v2 + v3)) * ef;
        q = (t < tmax) ? nq : q;  // uniform predicate (masked steps keep q)
    };
    auto renorm = [&]() {  // uniform rescale; alpha = C + log q invariant
        const float mm = readlane_f(q, 0);
        q *= __builtin_amdgcn_rcpf(mm);
        C += __logf(mm);
    };

    // clamped feats load (value unused past tmax; address stays in-bounds)
#define LDT(t) fl[(size_t)(((t) < kS - 1) ? (t) : (kS - 1)) * kT]

    // ---- main scan: two 8-step phases per iteration ----
    float pA0, pA1, pA2, pA3, pA4, pA5, pA6, pA7;  // raw feats in flight
    float pB0, pB1, pB2, pB3, pB4, pB5, pB6, pB7;
    float eA0, eA1, eA2, eA3, eA4, eA5, eA6, eA7;  // exp'd, ready to use
    float eB0, eB1, eB2, eB3, eB4, eB5, eB6, eB7;

    pA0 = LDT(1); pA1 = LDT(2); pA2 = LDT(3); pA3 = LDT(4);
    pA4 = LDT(5); pA5 = LDT(6); pA6 = LDT(7); pA7 = LDT(8);
    eA0 = __expf(pA0); eA1 = __expf(pA1); eA2 = __expf(pA2); eA3 = __expf(pA3);
    eA4 = __expf(pA4); eA5 = __expf(pA5); eA6 = __expf(pA6); eA7 = __expf(pA7);

    int t0 = 1;
    while (t0 < tmax) {
        // issue next phase's loads, compute current phase, then exp the loads
        pB0 = LDT(t0 + 8);  pB1 = LDT(t0 + 9);  pB2 = LDT(t0 + 10); pB3 = LDT(t0 + 11);
        pB4 = LDT(t0 + 12); pB5 = LDT(t0 + 13); pB6 = LDT(t0 + 14); pB7 = LDT(t0 + 15);
        dostep(eA0, t0 + 0); dostep(eA1, t0 + 1); dostep(eA2, t0 + 2); dostep(eA3, t0 + 3);
        renorm();
        dostep(eA4, t0 + 4); dostep(eA5, t0 + 5); dostep(eA6, t0 + 6); dostep(eA7, t0 + 7);
        renorm();
        eB0 = __expf(pB0); eB1 = __expf(pB1); eB2 = __expf(pB2); eB3 = __expf(pB3);
        eB4 = __expf(pB4); eB5 = __expf(pB5); eB6 = __expf(pB6); eB7 = __expf(pB7);

        pA0 = LDT(t0 + 16); pA1 = LDT(t0 + 17); pA2 = LDT(t0 + 18); pA3 = LDT(t0 + 19);
        pA4 = LDT(t0 + 20); pA5 = LDT(t0 + 21); pA6 = LDT(t0 + 22); pA7 = LDT(t0 + 23);
        dostep(eB0, t0 + 8);  dostep(eB1, t0 + 9);  dostep(eB2, t0 + 10); dostep(eB3, t0 + 11);
        renorm();
        dostep(eB4, t0 + 12); dostep(eB5, t0 + 13); dostep(eB6, t0 + 14); dostep(eB7, t0 + 15);
        renorm();
        eA0 = __expf(pA0); eA1 = __expf(pA1); eA2 = __expf(pA2); eA3 = __expf(pA3);
        eA4 = __expf(pA4); eA5 = __expf(pA5); eA6 = __expf(pA6); eA7 = __expf(pA7);
        t0 += 16;
    }

    // ---- forward score: C + log(sum_i q_i * exp(trans[i][END])) ----
    const float ssum = wave_sum(q * ME);  // lanes >= 36 contribute 0 (ME=0)
    const float forward_b = C + __logf(ssum);

    // ---- gold score (parallel over time steps) ----
    float g = 0.f;
    for (int k = j; k < kS; k += 64) {
        if (k < len) {
            const int tg = tb[k];
            const int pv = (k == 0) ? kStart : tb[k - 1];
            g += fbase[(size_t)k * kT + tg] + trans[pv * kT + tg];
        }
    }
    g = wave_sum(g);

    if (j == 0) {
        g += trans[tb[len - 1] * kT + kEnd];
        atomicAdd(out, (forward_b - g) * (1.0f / kB));
    }
}

}  // namespace

extern "C" void kernel_launch(void* const* d_in, const int* in_sizes, int n_in,
                              void* d_out, int out_size, void* d_ws, size_t ws_size,
                              hipStream_t stream) {
    const float* feats = (const float*)d_in[0];
    const float* trans = (const float*)d_in[1];
    const int* mask = (const int*)d_in[2];
    const int* tags = (const int*)d_in[3];
    float* out = (float*)d_out;

    hipMemsetAsync(out, 0, sizeof(float), stream);
    crf_nll_kernel<<<dim3(kB), dim3(64), 0, stream>>>(feats, trans, mask, tags, out);
}

// Round 7
// 125.533 us; speedup vs baseline: 1.2027x; 1.2027x over previous
//
#include <hip/hip_runtime.h>
#include <hip/hip_bf16.h>

// CRF NLL via chunk-parallel linear-space scan.
//   q_t^T = q_0^T (M D_1)(M D_2)...(M D_T),  M = exp(trans), D_t = diag(exp(f_t))
// Kernel 1 (crf_chunk): one wave per (batch, chunk): builds H_chunk = G_chunk^T
//   by H <- diag(e_t) M^T H (t ascending), 18x mfma_f32_16x16x32_bf16 per step,
//   H round-trips LDS in bf16 (stored [n*kHStr + m]: C-write and B-read both
//   contiguous). Renorm by H[1,1] every 4 steps (logscale accumulated).
// Kernel 2 (crf_combine): per batch: q0 then q <- H_p q for p=0..P-1 (readlane
//   matvec), final END-logsumexp + gold score -> atomicAdd.
// Masked steps (contiguous prefix, wave-uniform len): chunk loop stops at len;
// fully-masked chunks store identity.
//
// R5 failed to COMPILE: __hip_bfloat162 is not trivially copyable ->
// __builtin_bit_cast rejected (9 PACKW x 2 casts = the 18 errors). R6 packs
// via a __bf16 ext-vector (trivially copyable) with direct (__bf16) casts.
// No logic change.
//
// R0-R4 history: wave-serial matvec scan plateaued at ~400 cyc/step (VALUBusy
// 5.4%, 12.5% SIMDs busy, MfmaUtil 0) across spill-fix/broadcast/pipelining
// variants -> structural latency limit. This structure trades 36x more FLOPs
// (matrix vs vector scan) for 8x parallelism + MFMA throughput.

namespace {
constexpr int kB = 128;
constexpr int kS = 512;
constexpr int kT = 36;
constexpr int kStart = 34;
constexpr int kEnd = 35;
constexpr int kP = 8;      // chunks
constexpr int kL = 64;     // time-steps per chunk
constexpr int kHStr = 72;  // Hlds row stride in halfwords (144 B = 9*16, 16B-aligned rows)
constexpr int kEStr = 48;  // Etab row stride in floats

typedef __bf16 bf16x8 __attribute__((ext_vector_type(8)));
typedef __bf16 bf16x4 __attribute__((ext_vector_type(4)));
typedef float f32x4 __attribute__((ext_vector_type(4)));

__device__ __forceinline__ float readlane_f(float v, int lane) {
    return __builtin_bit_cast(float, __builtin_amdgcn_readlane(__builtin_bit_cast(int, v), lane));
}

__device__ __forceinline__ float wave_sum(float v) {
#pragma unroll
    for (int off = 32; off; off >>= 1) v += __shfl_xor(v, off, 64);
    return v;
}

__device__ __forceinline__ int wave_sum_i(int v) {
#pragma unroll
    for (int off = 32; off; off >>= 1) v += __shfl_xor(v, off, 64);
    return v;
}

// ============================ kernel 1: chunks ============================

__global__ __attribute__((amdgpu_flat_work_group_size(64, 64),
                          amdgpu_waves_per_eu(1, 1)))
void crf_chunk_kernel(const float* __restrict__ feats,   // (B,S,T)
                      const float* __restrict__ trans,   // (T,T)
                      const int* __restrict__ mask,      // (B,S)
                      float* __restrict__ Hws,           // (B,P,36,36)
                      float* __restrict__ lscws) {       // (B,P)
    const int b = blockIdx.x;
    const int p = blockIdx.y;
    const int tid = threadIdx.x;
    const int ln = tid & 15;    // n / col-of-tile index
    const int quad = tid >> 4;  // k/row quad index

    __shared__ __align__(16) unsigned short Hlds[48 * kHStr];  // H[m][n] at [n*kHStr + m], bf16
    __shared__ __align__(16) float Etab[kL * kEStr];           // exp(feats) per step

    // ---- sequence length (contiguous-prefix mask) ----
    const int* mb = mask + b * kS;
    int len = 0;
    for (int k = tid; k < kS; k += 64) len += mb[k];
    len = wave_sum_i(len);  // in [256, 512]

    float* Hout = Hws + (size_t)(b * kP + p) * (kT * kT);
    const int cs = (p == 0) ? 1 : p * kL;       // first scan step of chunk
    const int ce = min((p + 1) * kL, len);      // one past last
    const int nsteps = ce - cs;

    if (nsteps <= 0) {  // fully masked chunk -> identity transfer matrix
        for (int idx = tid; idx < kT * kT; idx += 64)
            Hout[idx] = (idx / kT == idx % kT) ? 1.f : 0.f;
        if (tid == 0) lscws[b * kP + p] = 0.f;
        return;
    }

    // ---- init H = I (36-subspace), zero padding ----
    for (int idx = tid; idx < 48 * kHStr; idx += 64) Hlds[idx] = 0;
    for (int r = tid; r < kT; r += 64) Hlds[r * kHStr + r] = 0x3F80;  // bf16 1.0

    // ---- stage exp(feats) for the chunk: Etab[tl][j], 1.0 in j-padding ----
    const float* fb = feats + ((size_t)b * kS + cs) * kT;
    for (int idx = tid; idx < kL * kEStr; idx += 64) {
        const int tl = idx / kEStr, jj = idx % kEStr;
        Etab[idx] = (jj < kT) ? __expf(fb[tl * kT + jj]) : 1.0f;
    }

    // ---- A = M^T in bf16 fragments (fixed): A[j][k] = exp(trans[k][j]) ----
    // mfma_f32_16x16x32_bf16 A-layout: m = lane&15, k = quad*8 + e
    auto afrag = [&](int rt, int kc) {
        bf16x8 r;
        const int j = rt * 16 + ln;
#pragma unroll
        for (int e = 0; e < 8; ++e) {
            const int k = kc * 32 + quad * 8 + e;
            float v = 0.f;
            if (k < kT && j < kT) v = __expf(trans[k * kT + j]);
            r[e] = (__bf16)v;
        }
        return r;
    };
    const bf16x8 a00 = afrag(0, 0), a01 = afrag(0, 1);
    const bf16x8 a10 = afrag(1, 0), a11 = afrag(1, 1);
    const bf16x8 a20 = afrag(2, 0), a21 = afrag(2, 1);

    // ---- main chunk loop ----
    float logC = 0.f;
    f32x4 c00, c01, c02, c10, c11, c12, c20, c21, c22;
    const f32x4 z = {0.f, 0.f, 0.f, 0.f};

    for (int tl = 0; tl < nsteps; ++tl) {
        // B fragments: B-layout n = lane&15, k = quad*8+e contiguous
#define BRD_LDS(kc, ct) (*(const bf16x8*)&Hlds[((ct)*16 + ln) * kHStr + (kc)*32 + quad * 8])
        const bf16x8 b00 = BRD_LDS(0, 0), b01 = BRD_LDS(0, 1), b02 = BRD_LDS(0, 2);
        const bf16x8 b10 = BRD_LDS(1, 0), b11 = BRD_LDS(1, 1), b12 = BRD_LDS(1, 2);
        // row scales e[m], m = rt*16 + quad*4 + reg (C/D row layout)
        const f32x4 e0 = *(const f32x4*)&Etab[tl * kEStr + 0 + quad * 4];
        const f32x4 e1 = *(const f32x4*)&Etab[tl * kEStr + 16 + quad * 4];
        const f32x4 e2 = *(const f32x4*)&Etab[tl * kEStr + 32 + quad * 4];

        c00 = __builtin_amdgcn_mfma_f32_16x16x32_bf16(a00, b00, z, 0, 0, 0);
        c00 = __builtin_amdgcn_mfma_f32_16x16x32_bf16(a01, b10, c00, 0, 0, 0);
        c01 = __builtin_amdgcn_mfma_f32_16x16x32_bf16(a00, b01, z, 0, 0, 0);
        c01 = __builtin_amdgcn_mfma_f32_16x16x32_bf16(a01, b11, c01, 0, 0, 0);
        c02 = __builtin_amdgcn_mfma_f32_16x16x32_bf16(a00, b02, z, 0, 0, 0);
        c02 = __builtin_amdgcn_mfma_f32_16x16x32_bf16(a01, b12, c02, 0, 0, 0);
        c10 = __builtin_amdgcn_mfma_f32_16x16x32_bf16(a10, b00, z, 0, 0, 0);
        c10 = __builtin_amdgcn_mfma_f32_16x16x32_bf16(a11, b10, c10, 0, 0, 0);
        c11 = __builtin_amdgcn_mfma_f32_16x16x32_bf16(a10, b01, z, 0, 0, 0);
        c11 = __builtin_amdgcn_mfma_f32_16x16x32_bf16(a11, b11, c11, 0, 0, 0);
        c12 = __builtin_amdgcn_mfma_f32_16x16x32_bf16(a10, b02, z, 0, 0, 0);
        c12 = __builtin_amdgcn_mfma_f32_16x16x32_bf16(a11, b12, c12, 0, 0, 0);
        c20 = __builtin_amdgcn_mfma_f32_16x16x32_bf16(a20, b00, z, 0, 0, 0);
        c20 = __builtin_amdgcn_mfma_f32_16x16x32_bf16(a21, b10, c20, 0, 0, 0);
        c21 = __builtin_amdgcn_mfma_f32_16x16x32_bf16(a20, b01, z, 0, 0, 0);
        c21 = __builtin_amdgcn_mfma_f32_16x16x32_bf16(a21, b11, c21, 0, 0, 0);
        c22 = __builtin_amdgcn_mfma_f32_16x16x32_bf16(a20, b02, z, 0, 0, 0);
        c22 = __builtin_amdgcn_mfma_f32_16x16x32_bf16(a21, b12, c22, 0, 0, 0);

        // renorm every 4 steps by H[1,1] (tile 00, lane 1, reg 1; positive)
        float rs = 1.f;
        if ((tl & 3) == 3) {
            const float s = readlane_f(c00[1], 1);
            rs = __builtin_amdgcn_rcpf(s);
            logC += __logf(s);
        }
        const f32x4 s0 = e0 * rs, s1 = e1 * rs, s2 = e2 * rs;
        c00 *= s0; c01 *= s0; c02 *= s0;
        c10 *= s1; c11 *= s1; c12 *= s1;
        c20 *= s2; c21 *= s2; c22 *= s2;

        // pack to bf16 and write back (4 consecutive m at fixed n: one b64)
#define PACKW(cv, rt, ct) {                                                     \
        bf16x4 hw;                                                              \
        hw[0] = (__bf16)cv[0]; hw[1] = (__bf16)cv[1];                           \
        hw[2] = (__bf16)cv[2]; hw[3] = (__bf16)cv[3];                           \
        *(bf16x4*)&Hlds[((ct)*16 + ln) * kHStr + (rt)*16 + quad * 4] = hw; }
        PACKW(c00, 0, 0) PACKW(c01, 0, 1) PACKW(c02, 0, 2)
        PACKW(c10, 1, 0) PACKW(c11, 1, 1) PACKW(c12, 1, 2)
        PACKW(c20, 2, 0) PACKW(c21, 2, 1) PACKW(c22, 2, 2)
    }

    // ---- store H (fp32 from C regs) + logscale ----
#define STORE_T(cv, rt, ct) {                                   \
    const int rr = (ct)*16 + ln;                                \
    _Pragma("unroll") for (int reg = 0; reg < 4; ++reg) {       \
        const int mm2 = (rt)*16 + quad * 4 + reg;               \
        if (mm2 < kT && rr < kT) Hout[mm2 * kT + rr] = cv[reg]; } }
    STORE_T(c00, 0, 0) STORE_T(c01, 0, 1) STORE_T(c02, 0, 2)
    STORE_T(c10, 1, 0) STORE_T(c11, 1, 1) STORE_T(c12, 1, 2)
    STORE_T(c20, 2, 0) STORE_T(c21, 2, 1) STORE_T(c22, 2, 2)
    if (tid == 0) lscws[b * kP + p] = logC;
}

// ============================ kernel 2: combine ============================

// term n of the 36-dot: accumulator a (0..3), h-vector g (0..8), component c
#define FORK36(X) \
    X(0,0,0,0) X(1,1,0,1) X(2,2,0,2) X(3,3,0,3) \
    X(4,0,1,0) X(5,1,1,1) X(6,2,1,2) X(7,3,1,3) \
    X(8,0,2,0) X(9,1,2,1) X(10,2,2,2) X(11,3,2,3) \
    X(12,0,3,0) X(13,1,3,1) X(14,2,3,2) X(15,3,3,3) \
    X(16,0,4,0) X(17,1,4,1) X(18,2,4,2) X(19,3,4,3) \
    X(20,0,5,0) X(21,1,5,1) X(22,2,5,2) X(23,3,5,3) \
    X(24,0,6,0) X(25,1,6,1) X(26,2,6,2) X(27,3,6,3) \
    X(28,0,7,0) X(29,1,7,1) X(30,2,7,2) X(31,3,7,3) \
    X(32,0,8,0) X(33,1,8,1) X(34,2,8,2) X(35,3,8,3)

__global__ __attribute__((amdgpu_flat_work_group_size(64, 64),
                          amdgpu_waves_per_eu(1, 1)))
void crf_combine_kernel(const float* __restrict__ feats,
                        const float* __restrict__ trans,
                        const int* __restrict__ mask,
                        const int* __restrict__ tags,
                        const float* __restrict__ Hws,
                        const float* __restrict__ lscws,
                        float* __restrict__ out) {
    const int b = blockIdx.x;
    const int j = threadIdx.x;
    const float* fbase = feats + (size_t)b * kS * kT;
    const int* mb = mask + b * kS;
    const int* tb = tags + b * kS;

    int len = 0;
    for (int k = j; k < kS; k += 64) len += mb[k];
    len = wave_sum_i(len);

    const float ME = (j < kT) ? __expf(trans[j * kT + kEnd]) : 0.f;

    // init: alpha0 = feats[b,0,:] + trans[START,:]
    float a0 = -1e30f;
    if (j < kT) a0 = fbase[j] + trans[kStart * kT + j];
    float C = readlane_f(a0, 0);
    float q = __expf(a0 - C);  // lanes >= 36 -> 0

    const int jr = (j < kT) ? j : 0;  // clamped row for loads
#pragma unroll
    for (int p = 0; p < kP; ++p) {
        const float* rp = Hws + (size_t)(b * kP + p) * (kT * kT) + jr * kT;
        const f32x4 h0 = *(const f32x4*)(rp + 0);
        const f32x4 h1 = *(const f32x4*)(rp + 4);
        const f32x4 h2 = *(const f32x4*)(rp + 8);
        const f32x4 h3 = *(const f32x4*)(rp + 12);
        const f32x4 h4 = *(const f32x4*)(rp + 16);
        const f32x4 h5 = *(const f32x4*)(rp + 20);
        const f32x4 h6 = *(const f32x4*)(rp + 24);
        const f32x4 h7 = *(const f32x4*)(rp + 28);
        const f32x4 h8 = *(const f32x4*)(rp + 32);
#define BRD2(n, a, g, c) const float bb##n = readlane_f(q, n);
        FORK36(BRD2)
#undef BRD2
        float v0 = 0.f, v1 = 0.f, v2 = 0.f, v3 = 0.f;
#define FMA2(n, a, g, c) v##a = fmaf(bb##n, h##g[c], v##a);
        FORK36(FMA2)
#undef FMA2
        const float qn = (v0 + v1) + (v2 + v3);
        q = (j < kT) ? qn : 0.f;
        C += lscws[b * kP + p];
        const float s = readlane_f(q, 0);  // positive (state-0 alpha)
        q *= __builtin_amdgcn_rcpf(s);
        C += __logf(s);
    }

    // forward score
    const float ssum = wave_sum(q * ME);
    const float forward_b = C + __logf(ssum);

    // gold score
    float g = 0.f;
    for (int k = j; k < kS; k += 64) {
        if (k < len) {
            const int tg = tb[k];
            const int pv = (k == 0) ? kStart : tb[k - 1];
            g += fbase[(size_t)k * kT + tg] + trans[pv * kT + tg];
        }
    }
    g = wave_sum(g);

    if (j == 0) {
        g += trans[tb[len - 1] * kT + kEnd];
        atomicAdd(out, (forward_b - g) * (1.0f / kB));
    }
}

}  // namespace

extern "C" void kernel_launch(void* const* d_in, const int* in_sizes, int n_in,
                              void* d_out, int out_size, void* d_ws, size_t ws_size,
                              hipStream_t stream) {
    const float* feats = (const float*)d_in[0];
    const float* trans = (const float*)d_in[1];
    const int* mask = (const int*)d_in[2];
    const int* tags = (const int*)d_in[3];
    float* out = (float*)d_out;

    float* Hws = (float*)d_ws;                       // B*P*36*36 fp32 = 5.2 MB
    float* lscws = Hws + (size_t)kB * kP * kT * kT;  // B*P fp32

    (void)hipMemsetAsync(out, 0, sizeof(float), stream);
    crf_chunk_kernel<<<dim3(kB, kP), dim3(64), 0, stream>>>(feats, trans, mask, Hws, lscws);
    crf_combine_kernel<<<dim3(kB), dim3(64), 0, stream>>>(feats, trans, mask, tags,
                                                          Hws, lscws, out);
}

// Round 8
// 109.645 us; speedup vs baseline: 1.3770x; 1.1449x over previous
//
#include <hip/hip_runtime.h>
#include <hip/hip_bf16.h>

// CRF NLL via chunk-parallel linear-space scan.
//   q_t^T = q_0^T (M D_1)(M D_2)...(M D_T),  M = exp(trans), D_t = diag(exp(f_t))
// Kernel 1 (crf_chunk): one wave per (batch, chunk): H <- diag(e_t) M^T H,
//   18x mfma_f32_16x16x32_bf16 per step, H round-trips LDS in bf16.
// Kernel 2 (crf_combine): per batch: q <- H_p q (readlane matvec) + gold score.
//
// R7 vs R6 (R6: chunk kernel 60us, MfmaUtil 8.4%, VALUBusy 15%, 1 wave/SIMD,
// ~2250 cyc/step vs ~600 cyc serial chain -> latency fully exposed):
//  - P 8->16 (2048 waves = 2/SIMD) + waves_per_eu(2,4) (256-VGPR budget, no
//    spill at 132) -> co-resident waves hide the ds_read->MFMA->pack->ds_write
//    chain.
//  - renorm by STALE H[1,1] read from LDS at loop top (uniform positive scale
//    is exact: its log is re-added; rcp err 2^-22 negligible) -> removes the
//    MFMA->VALU readlane hazard + log from the per-step critical path.
//  - H chunk matrices stored bf16 (5.3 MB ws), Etab stride 64.

namespace {
constexpr int kB = 128;
constexpr int kS = 512;
constexpr int kT = 36;
constexpr int kStart = 34;
constexpr int kEnd = 35;
constexpr int kP = 16;     // chunks
constexpr int kL = 32;     // time-steps per chunk
constexpr int kHStr = 72;  // Hlds row stride in halfwords (144 B, 16B-aligned rows)
constexpr int kEStr = 64;  // Etab row stride in floats (shift indexing)

typedef __bf16 bf16x8 __attribute__((ext_vector_type(8)));
typedef __bf16 bf16x4 __attribute__((ext_vector_type(4)));
typedef float f32x4 __attribute__((ext_vector_type(4)));

__device__ __forceinline__ float readlane_f(float v, int lane) {
    return __builtin_bit_cast(float, __builtin_amdgcn_readlane(__builtin_bit_cast(int, v), lane));
}

__device__ __forceinline__ float wave_sum(float v) {
#pragma unroll
    for (int off = 32; off; off >>= 1) v += __shfl_xor(v, off, 64);
    return v;
}

__device__ __forceinline__ int wave_sum_i(int v) {
#pragma unroll
    for (int off = 32; off; off >>= 1) v += __shfl_xor(v, off, 64);
    return v;
}

// ============================ kernel 1: chunks ============================

__global__ __attribute__((amdgpu_flat_work_group_size(64, 64),
                          amdgpu_waves_per_eu(2, 4)))
void crf_chunk_kernel(const float* __restrict__ feats,    // (B,S,T)
                      const float* __restrict__ trans,    // (T,T)
                      const int* __restrict__ mask,       // (B,S)
                      __bf16* __restrict__ Hws,           // (B,P,36,36) bf16
                      float* __restrict__ lscws) {        // (B,P)
    const int b = blockIdx.x;
    const int p = blockIdx.y;
    const int tid = threadIdx.x;
    const int ln = tid & 15;    // n / col-of-tile index
    const int quad = tid >> 4;  // k/row quad index

    __shared__ __align__(16) unsigned short Hlds[48 * kHStr];  // H[m][n] at [n*kHStr+m], bf16
    __shared__ __align__(16) float Etab[kL * kEStr];           // exp(feats) per step

    // ---- sequence length (contiguous-prefix mask) ----
    const int* mb = mask + b * kS;
    int len = 0;
    for (int k = tid; k < kS; k += 64) len += mb[k];
    len = wave_sum_i(len);  // in [256, 512]

    __bf16* Hout = Hws + (size_t)(b * kP + p) * (kT * kT);
    const int cs = (p == 0) ? 1 : p * kL;       // first scan step of chunk
    const int ce = min((p + 1) * kL, len);      // one past last
    const int nsteps = ce - cs;

    if (nsteps <= 0) {  // fully masked chunk -> identity transfer matrix
        for (int idx = tid; idx < kT * kT; idx += 64)
            Hout[idx] = (__bf16)((idx / kT == idx % kT) ? 1.f : 0.f);
        if (tid == 0) lscws[b * kP + p] = 0.f;
        return;
    }

    // ---- init H = I (36-subspace), zero padding ----
    for (int idx = tid; idx < 48 * kHStr; idx += 64) Hlds[idx] = 0;
    for (int r = tid; r < kT; r += 64) Hlds[r * kHStr + r] = 0x3F80;  // bf16 1.0

    // ---- stage exp(feats): Etab[tl][j], 1.0 in j-padding ----
    const float* fb = feats + ((size_t)b * kS + cs) * kT;
    for (int tl2 = 0; tl2 < kL; ++tl2)
        Etab[tl2 * kEStr + tid] = (tid < kT) ? __expf(fb[tl2 * kT + tid]) : 1.0f;

    // ---- A = M^T in bf16 fragments (fixed): A[j][k] = exp(trans[k][j]) ----
    // mfma_f32_16x16x32_bf16 A-layout: m = lane&15, k = quad*8 + e
    auto afrag = [&](int rt, int kc) {
        bf16x8 r;
        const int j = rt * 16 + ln;
#pragma unroll
        for (int e = 0; e < 8; ++e) {
            const int k = kc * 32 + quad * 8 + e;
            float v = 0.f;
            if (k < kT && j < kT) v = __expf(trans[k * kT + j]);
            r[e] = (__bf16)v;
        }
        return r;
    };
    const bf16x8 a00 = afrag(0, 0), a01 = afrag(0, 1);
    const bf16x8 a10 = afrag(1, 0), a11 = afrag(1, 1);
    const bf16x8 a20 = afrag(2, 0), a21 = afrag(2, 1);

    // ---- main chunk loop ----
    float logC = 0.f;
    f32x4 c00, c01, c02, c10, c11, c12, c20, c21, c22;
    const f32x4 z = {0.f, 0.f, 0.f, 0.f};

    for (int tl = 0; tl < nsteps; ++tl) {
        // stale renorm source: H[1,1] as written LAST step (uniform, positive)
        const unsigned short sraw = Hlds[kHStr + 1];
        // B fragments: lane ln holds B[k = kc*32+quad*8+e][n = ct*16+ln]
#define BRD_LDS(kc, ct) (*(const bf16x8*)&Hlds[((ct)*16 + ln) * kHStr + (kc)*32 + quad * 8])
        const bf16x8 b00 = BRD_LDS(0, 0), b01 = BRD_LDS(0, 1), b02 = BRD_LDS(0, 2);
        const bf16x8 b10 = BRD_LDS(1, 0), b11 = BRD_LDS(1, 1), b12 = BRD_LDS(1, 2);
        // row scales e[m], m = rt*16 + quad*4 + reg (C/D row layout)
        const f32x4 e0 = *(const f32x4*)&Etab[tl * kEStr + 0 + quad * 4];
        const f32x4 e1 = *(const f32x4*)&Etab[tl * kEStr + 16 + quad * 4];
        const f32x4 e2 = *(const f32x4*)&Etab[tl * kEStr + 32 + quad * 4];

        c00 = __builtin_amdgcn_mfma_f32_16x16x32_bf16(a00, b00, z, 0, 0, 0);
        c00 = __builtin_amdgcn_mfma_f32_16x16x32_bf16(a01, b10, c00, 0, 0, 0);
        c01 = __builtin_amdgcn_mfma_f32_16x16x32_bf16(a00, b01, z, 0, 0, 0);
        c01 = __builtin_amdgcn_mfma_f32_16x16x32_bf16(a01, b11, c01, 0, 0, 0);
        c02 = __builtin_amdgcn_mfma_f32_16x16x32_bf16(a00, b02, z, 0, 0, 0);
        c02 = __builtin_amdgcn_mfma_f32_16x16x32_bf16(a01, b12, c02, 0, 0, 0);
        c10 = __builtin_amdgcn_mfma_f32_16x16x32_bf16(a10, b00, z, 0, 0, 0);
        c10 = __builtin_amdgcn_mfma_f32_16x16x32_bf16(a11, b10, c10, 0, 0, 0);
        c11 = __builtin_amdgcn_mfma_f32_16x16x32_bf16(a10, b01, z, 0, 0, 0);
        c11 = __builtin_amdgcn_mfma_f32_16x16x32_bf16(a11, b11, c11, 0, 0, 0);
        c12 = __builtin_amdgcn_mfma_f32_16x16x32_bf16(a10, b02, z, 0, 0, 0);
        c12 = __builtin_amdgcn_mfma_f32_16x16x32_bf16(a11, b12, c12, 0, 0, 0);
        c20 = __builtin_amdgcn_mfma_f32_16x16x32_bf16(a20, b00, z, 0, 0, 0);
        c20 = __builtin_amdgcn_mfma_f32_16x16x32_bf16(a21, b10, c20, 0, 0, 0);
        c21 = __builtin_amdgcn_mfma_f32_16x16x32_bf16(a20, b01, z, 0, 0, 0);
        c21 = __builtin_amdgcn_mfma_f32_16x16x32_bf16(a21, b11, c21, 0, 0, 0);
        c22 = __builtin_amdgcn_mfma_f32_16x16x32_bf16(a20, b02, z, 0, 0, 0);
        c22 = __builtin_amdgcn_mfma_f32_16x16x32_bf16(a21, b12, c22, 0, 0, 0);

        // renorm every 4 steps by the stale H[1,1] (off the MFMA result path)
        float rs = 1.f;
        if ((tl & 3) == 3) {
            const float s = __builtin_bit_cast(float, (unsigned int)sraw << 16);
            rs = __builtin_amdgcn_rcpf(s);
            logC += __logf(s);
        }
        const f32x4 s0 = e0 * rs, s1 = e1 * rs, s2 = e2 * rs;
        c00 *= s0; c01 *= s0; c02 *= s0;
        c10 *= s1; c11 *= s1; c12 *= s1;
        c20 *= s2; c21 *= s2; c22 *= s2;

        // pack to bf16 and write back (4 consecutive m at fixed n: one b64)
#define PACKW(cv, rt, ct) {                                                     \
        bf16x4 hw;                                                              \
        hw[0] = (__bf16)cv[0]; hw[1] = (__bf16)cv[1];                           \
        hw[2] = (__bf16)cv[2]; hw[3] = (__bf16)cv[3];                           \
        *(bf16x4*)&Hlds[((ct)*16 + ln) * kHStr + (rt)*16 + quad * 4] = hw; }
        PACKW(c00, 0, 0) PACKW(c01, 0, 1) PACKW(c02, 0, 2)
        PACKW(c10, 1, 0) PACKW(c11, 1, 1) PACKW(c12, 1, 2)
        PACKW(c20, 2, 0) PACKW(c21, 2, 1) PACKW(c22, 2, 2)
    }

    // ---- store H (bf16) + logscale ----
#define STORE_T(cv, rt, ct) {                                     \
    const int rr = (ct)*16 + ln;                                  \
    _Pragma("unroll") for (int reg = 0; reg < 4; ++reg) {         \
        const int mm2 = (rt)*16 + quad * 4 + reg;                 \
        if (mm2 < kT && rr < kT) Hout[mm2 * kT + rr] = (__bf16)cv[reg]; } }
    STORE_T(c00, 0, 0) STORE_T(c01, 0, 1) STORE_T(c02, 0, 2)
    STORE_T(c10, 1, 0) STORE_T(c11, 1, 1) STORE_T(c12, 1, 2)
    STORE_T(c20, 2, 0) STORE_T(c21, 2, 1) STORE_T(c22, 2, 2)
    if (tid == 0) lscws[b * kP + p] = logC;
}

// ============================ kernel 2: combine ============================

// term n of the 36-dot: accumulator a (0..3), h-vector g (= n/4), component c (= n%4)
#define FORK36(X) \
    X(0,0,0,0) X(1,1,0,1) X(2,2,0,2) X(3,3,0,3) \
    X(4,0,1,0) X(5,1,1,1) X(6,2,1,2) X(7,3,1,3) \
    X(8,0,2,0) X(9,1,2,1) X(10,2,2,2) X(11,3,2,3) \
    X(12,0,3,0) X(13,1,3,1) X(14,2,3,2) X(15,3,3,3) \
    X(16,0,4,0) X(17,1,4,1) X(18,2,4,2) X(19,3,4,3) \
    X(20,0,5,0) X(21,1,5,1) X(22,2,5,2) X(23,3,5,3) \
    X(24,0,6,0) X(25,1,6,1) X(26,2,6,2) X(27,3,6,3) \
    X(28,0,7,0) X(29,1,7,1) X(30,2,7,2) X(31,3,7,3) \
    X(32,0,8,0) X(33,1,8,1) X(34,2,8,2) X(35,3,8,3)

__global__ __attribute__((amdgpu_flat_work_group_size(64, 64),
                          amdgpu_waves_per_eu(1, 1)))
void crf_combine_kernel(const float* __restrict__ feats,
                        const float* __restrict__ trans,
                        const int* __restrict__ mask,
                        const int* __restrict__ tags,
                        const __bf16* __restrict__ Hws,
                        const float* __restrict__ lscws,
                        float* __restrict__ out) {
    const int b = blockIdx.x;
    const int j = threadIdx.x;
    const float* fbase = feats + (size_t)b * kS * kT;
    const int* mb = mask + b * kS;
    const int* tb = tags + b * kS;

    int len = 0;
    for (int k = j; k < kS; k += 64) len += mb[k];
    len = wave_sum_i(len);

    const float ME = (j < kT) ? __expf(trans[j * kT + kEnd]) : 0.f;

    // init: alpha0 = feats[b,0,:] + trans[START,:]
    float a0 = -1e30f;
    if (j < kT) a0 = fbase[j] + trans[kStart * kT + j];
    float C = readlane_f(a0, 0);
    float q = __expf(a0 - C);  // lanes >= 36 -> 0

    const int jr = (j < kT) ? j : 0;  // clamped row for loads
#pragma unroll
    for (int p = 0; p < kP; ++p) {
        const __bf16* rp = Hws + ((size_t)(b * kP + p) * kT + jr) * kT;  // 8B-aligned row
        const bf16x4 h0 = *(const bf16x4*)(rp + 0);
        const bf16x4 h1 = *(const bf16x4*)(rp + 4);
        const bf16x4 h2 = *(const bf16x4*)(rp + 8);
        const bf16x4 h3 = *(const bf16x4*)(rp + 12);
        const bf16x4 h4 = *(const bf16x4*)(rp + 16);
        const bf16x4 h5 = *(const bf16x4*)(rp + 20);
        const bf16x4 h6 = *(const bf16x4*)(rp + 24);
        const bf16x4 h7 = *(const bf16x4*)(rp + 28);
        const bf16x4 h8 = *(const bf16x4*)(rp + 32);
#define BRD2(n, a, g, c) const float bb##n = readlane_f(q, n);
        FORK36(BRD2)
#undef BRD2
        float v0 = 0.f, v1 = 0.f, v2 = 0.f, v3 = 0.f;
#define FMA2(n, a, g, c) v##a = fmaf(bb##n, (float)h##g[c], v##a);
        FORK36(FMA2)
#undef FMA2
        const float qn = (v0 + v1) + (v2 + v3);
        q = (j < kT) ? qn : 0.f;
        C += lscws[b * kP + p];
        const float s = readlane_f(q, 0);  // positive (state-0 alpha)
        q *= __builtin_amdgcn_rcpf(s);
        C += __logf(s);
    }

    // forward score
    const float ssum = wave_sum(q * ME);
    const float forward_b = C + __logf(ssum);

    // gold score
    float g = 0.f;
    for (int k = j; k < kS; k += 64) {
        if (k < len) {
            const int tg = tb[k];
            const int pv = (k == 0) ? kStart : tb[k - 1];
            g += fbase[(size_t)k * kT + tg] + trans[pv * kT + tg];
        }
    }
    g = wave_sum(g);

    if (j == 0) {
        g += trans[tb[len - 1] * kT + kEnd];
        atomicAdd(out, (forward_b - g) * (1.0f / kB));
    }
}

}  // namespace

extern "C" void kernel_launch(void* const* d_in, const int* in_sizes, int n_in,
                              void* d_out, int out_size, void* d_ws, size_t ws_size,
                              hipStream_t stream) {
    const float* feats = (const float*)d_in[0];
    const float* trans = (const float*)d_in[1];
    const int* mask = (const int*)d_in[2];
    const int* tags = (const int*)d_in[3];
    float* out = (float*)d_out;

    __bf16* Hws = (__bf16*)d_ws;                            // B*P*36*36 bf16 = 5.3 MB
    float* lscws = (float*)(Hws + (size_t)kB * kP * kT * kT);  // B*P fp32

    (void)hipMemsetAsync(out, 0, sizeof(float), stream);
    crf_chunk_kernel<<<dim3(kB, kP), dim3(64), 0, stream>>>(feats, trans, mask, Hws, lscws);
    crf_combine_kernel<<<dim3(kB), dim3(64), 0, stream>>>(feats, trans, mask, tags,
                                                          Hws, lscws, out);
}